// Round 10
// baseline (1453.596 us; speedup 1.0000x reference)
//
#include <hip/hip_runtime.h>

#define NB 8
#define NP 8192
#define SP 1024
#define KS 32
#define CD 64
#define MROWS (NB*SP*KS)
#define NCOPY 16

typedef float v2f __attribute__((ext_vector_type(2)));
typedef unsigned long long u64;

// DPP reduction steps: pure VALU, ctrl as template (builtin needs an immediate).
// old=src + bound_ctrl=false -> lanes with no valid source keep their own value
// (identity for max/min).
template <int CTRL>
__device__ __forceinline__ float dpp_fmax_step(float x) {
    int xi = __float_as_int(x);
    int si = __builtin_amdgcn_update_dpp(xi, xi, CTRL, 0xf, 0xf, false);
    return fmaxf(x, __int_as_float(si));
}
template <int CTRL>
__device__ __forceinline__ unsigned dpp_umin_step(unsigned x) {
    int si = __builtin_amdgcn_update_dpp((int)x, (int)x, CTRL, 0xf, 0xf, false);
    unsigned s = (unsigned)si;
    return x < s ? x : s;
}

// ---------------- fused FPS (blocks 0..7) + points-transpose (8..1031) + weight-prep (1032) ----------
// FPS: 1024 thr, 8 pts/thread, zero global mem in loop, ONE barrier/iter.
// Argmax = two-pass: exact f32 max (DPP v_max_f32 ladder) then min-u32 index among
// achievers -> identical to jnp.argmax first-index semantics (no NaN, no -0 here).
__global__ __launch_bounds__(1024) void k_fps_pre(const float* __restrict__ xyz,
                                                  float* __restrict__ fps_pts,
                                                  float* __restrict__ out_nx,
                                                  const float* __restrict__ points,
                                                  float* __restrict__ pts_t,
                                                  const float* __restrict__ w0,
                                                  const float* __restrict__ w1,
                                                  const float* __restrict__ w2,
                                                  float* __restrict__ Wt0,
                                                  float* __restrict__ Wt1,
                                                  float* __restrict__ Wt2,
                                                  float* __restrict__ stats)
{
#pragma clang fp contract(off)
    __shared__ __align__(16) unsigned char smem[131072 + 256];
    const int blk = blockIdx.x;
    const int t = threadIdx.x;

    if (blk >= NB) {
        if (blk >= NB + NB * (NP / 64)) {
            // weight prep: zero stats, transpose weights to [kk][c]
            for (int i = t; i < 8192; i += 1024) stats[i] = 0.f;
            for (int i = t; i < 64 * 67; i += 1024) { int c = i / 67, kk = i % 67; Wt0[kk * 64 + c] = w0[i]; }
            for (int i = t; i < 64 * 64; i += 1024) { int c = i >> 6, kk = i & 63; Wt1[kk * 64 + c] = w1[i]; }
            for (int i = t; i < 128 * 64; i += 1024) { int c = i >> 6, kk = i & 63; Wt2[kk * 128 + c] = w2[i]; }
            return;
        }
        // points transpose (B,64,N) -> (B,N,64), 64x64 tile, 1024 threads
        float (*tile)[65] = (float(*)[65])smem;
        const int tblk = blk - NB;
        const int b = tblk >> 7;
        const int n0 = (tblk & 127) << 6;
        const float* pb = points + (size_t)b * CD * NP;
        const int c = t & 63;
        const int dr = t >> 6;                 // 0..15
#pragma unroll
        for (int it = 0; it < 4; ++it) {
            int d = dr + it * 16;
            tile[d][c] = pb[(size_t)d * NP + n0 + c];
        }
        __syncthreads();
#pragma unroll
        for (int it = 0; it < 4; ++it) {
            int nn = dr + it * 16;
            pts_t[((size_t)b * NP + n0 + nn) * CD + c] = tile[c][nn];
        }
        return;
    }

    // ---- FPS path ----
    float4* s_p = (float4*)smem;               // 128 KB xyz mirror
    u64 (*s_wk)[16] = (u64(*)[16])(smem + 131072);
    const int b = blk;
    const int lane = t & 63, wid = t >> 6;     // 16 waves
    const float* xb = xyz + (size_t)b * 3 * NP;
    v2f px[4], py[4], pz[4], dv[4];
    int gid[8];
#pragma unroll
    for (int j = 0; j < 4; ++j) {
        const int n0 = t + (2 * j) * 1024, n1 = n0 + 1024;
        px[j] = (v2f){xb[n0], xb[n1]};
        py[j] = (v2f){xb[NP + n0], xb[NP + n1]};
        pz[j] = (v2f){xb[2 * NP + n0], xb[2 * NP + n1]};
        dv[j] = (v2f){1e10f, 1e10f};
        s_p[n0] = make_float4(px[j].x, py[j].x, pz[j].x, 0.f);
        s_p[n1] = make_float4(px[j].y, py[j].y, pz[j].y, 0.f);
        gid[2 * j] = n0; gid[2 * j + 1] = n1;
    }
    float cx = xb[0], cy = xb[NP], cz = xb[2 * NP];
    float hx = 0.f, hy = 0.f, hz = 0.f;        // captured centroid of iteration i == t
    __syncthreads();
    for (int i = 0; i < SP; ++i) {
        if (i == t) { hx = cx; hy = cy; hz = cz; }
        // distance update + in-thread argmax (EXACT fp32: sub, mul, (x2+y2)+z2, min;
        // contract(off) forbids fma; ascending gid + strict > == first-index tie-break)
        float bv = -1.f; int bg = 0;
#pragma unroll
        for (int j = 0; j < 4; ++j) {
            v2f dx = px[j] - cx;
            v2f dy = py[j] - cy;
            v2f dz = pz[j] - cz;
            v2f d  = dx * dx + dy * dy;
            d = d + dz * dz;
            v2f dm = dv[j];
            dm.x = fminf(dm.x, d.x);
            dm.y = fminf(dm.y, d.y);
            dv[j] = dm;
            if (dm.x > bv) { bv = dm.x; bg = gid[2 * j]; }
            if (dm.y > bv) { bv = dm.y; bg = gid[2 * j + 1]; }
        }
        // wave two-pass argmax: value max ladder (lane63), then min-idx among achievers
        float rv = bv;
        rv = dpp_fmax_step<0x111>(rv);         // row_shr:1
        rv = dpp_fmax_step<0x112>(rv);         // row_shr:2
        rv = dpp_fmax_step<0x114>(rv);         // row_shr:4
        rv = dpp_fmax_step<0x118>(rv);         // row_shr:8
        rv = dpp_fmax_step<0x142>(rv);         // row_bcast:15
        rv = dpp_fmax_step<0x143>(rv);         // row_bcast:31
        const float wmax = __int_as_float(__builtin_amdgcn_readlane(__float_as_int(rv), 63));
        unsigned cand = (bv == wmax) ? (unsigned)bg : 0xFFFFFFFFu;
        cand = dpp_umin_step<0x111>(cand);
        cand = dpp_umin_step<0x112>(cand);
        cand = dpp_umin_step<0x114>(cand);
        cand = dpp_umin_step<0x118>(cand);
        cand = dpp_umin_step<0x142>(cand);
        cand = dpp_umin_step<0x143>(cand);     // lane63 = min gid achieving wmax
        const int par = i & 1;
        if (lane == 63)
            s_wk[par][wid] = ((u64)(unsigned)__float_as_int(wmax) << 32) | cand;
        __syncthreads();
        // cross-wave: every wave two-pass reduces the 16 leader pairs
        const u64 k = s_wk[par][lane & 15];
        const float lv = __int_as_float((int)(unsigned)(k >> 32));
        const unsigned li = (unsigned)k;
        float gv = lv;
        gv = dpp_fmax_step<0x111>(gv);
        gv = dpp_fmax_step<0x112>(gv);
        gv = dpp_fmax_step<0x114>(gv);
        gv = dpp_fmax_step<0x118>(gv);         // lane15 of each row = global max
        const float gmaxv = __int_as_float(__builtin_amdgcn_readlane(__float_as_int(gv), 15));
        unsigned c2 = (lv == gmaxv) ? li : 0xFFFFFFFFu;
        c2 = dpp_umin_step<0x111>(c2);
        c2 = dpp_umin_step<0x112>(c2);
        c2 = dpp_umin_step<0x114>(c2);
        c2 = dpp_umin_step<0x118>(c2);
        const int wg = __builtin_amdgcn_readlane((int)c2, 15);
        const float4 c = s_p[wg];              // uniform broadcast ds_read_b128
        cx = c.x; cy = c.y; cz = c.z;
        // safe without 2nd barrier: next write to s_wk[par] is 2 iters away, past the next barrier
    }
    // deferred outputs: thread t owns fps point t (SP == blockDim.x)
    fps_pts[(b * SP + t) * 3 + 0] = hx;
    fps_pts[(b * SP + t) * 3 + 1] = hy;
    fps_pts[(b * SP + t) * 3 + 2] = hz;
    out_nx[(size_t)b * 3 * SP + 0 * SP + t] = hx;
    out_nx[(size_t)b * 3 * SP + 1 * SP + t] = hy;
    out_nx[(size_t)b * 3 * SP + 2 * SP + t] = hz;
}

// ---------------- ball query: one wave per query, ordered first-32 append ----------------
__global__ __launch_bounds__(256) void k_ballquery(const float* __restrict__ xyz,
                                                   const float* __restrict__ fps_pts,
                                                   int* __restrict__ ball_idx)
{
    const int wib = threadIdx.x >> 6;
    const int lane = threadIdx.x & 63;
    const int wid = blockIdx.x * 4 + wib;          // b*SP + s
    const int b = wid >> 10;
    const float* xb = xyz + (size_t)b * 3 * NP;
    const float qx = fps_pts[wid * 3 + 0];
    const float qy = fps_pts[wid * 3 + 1];
    const float qz = fps_pts[wid * 3 + 2];
    __shared__ int s_list[4][KS];
    int* list = s_list[wib];
    const float r2 = (float)(0.2 * 0.2);           // 0.039999999f — matches python double->f32
    int found = 0;
    for (int base = 0; base < NP && found < KS; base += 64) {
        int n = base + lane;
        float dx = __fsub_rn(qx, xb[n]);
        float dy = __fsub_rn(qy, xb[NP + n]);
        float dz = __fsub_rn(qz, xb[2 * NP + n]);
        float d = __fadd_rn(__fadd_rn(__fmul_rn(dx, dx), __fmul_rn(dy, dy)), __fmul_rn(dz, dz));
        bool in = !(d > r2);
        unsigned long long m = __ballot(in);
        int before = __popcll(m & ((1ull << lane) - 1ull));
        int pos = found + before;
        if (in && pos < KS) list[pos] = n;
        found += __popcll(m);
    }
    int first = list[0];
    if (lane < KS) {
        int v = (lane < found) ? list[lane] : first;
        ball_idx[wid * KS + lane] = v;
    }
}

// ---------------- layer1: gather(feat 67) + GEMM(67->64) + stats ----------------
__global__ __launch_bounds__(256) void k_layer1(const float* __restrict__ xyz,
                                                const float* __restrict__ pts_t,
                                                const float* __restrict__ fps_pts,
                                                const int* __restrict__ ball_idx,
                                                const float* __restrict__ Wt0,
                                                const float* __restrict__ bias0,
                                                float* __restrict__ h1,
                                                float* __restrict__ sum0,
                                                float* __restrict__ ssq0)
{
    __shared__ __align__(16) float Ft[67 * 128];
    __shared__ __align__(16) float Ws[67 * 64];
    __shared__ int   s_idx[128];
    __shared__ float s_q[4][3];
    const int t = threadIdx.x;
    const int m0 = blockIdx.x * 128;
    const int g0 = m0 >> 5;
    const int b = g0 >> 10;
    if (t < 128) s_idx[t] = ball_idx[g0 * KS + t];
    if (t < 12) ((float*)s_q)[t] = fps_pts[g0 * 3 + t];
    for (int i = t; i < 67 * 64; i += 256) Ws[i] = Wt0[i];
    __syncthreads();
    {
        const int r = t >> 1, half = t & 1;
        const int n = s_idx[r];
        const float* prow = pts_t + ((size_t)b * NP + n) * CD;
#pragma unroll
        for (int rep = 0; rep < 8; ++rep) {
            const int c4 = half * 4 + rep * 8;
            float4 v = *(const float4*)(prow + c4);
            Ft[(3 + c4 + 0) * 128 + r] = v.x;
            Ft[(3 + c4 + 1) * 128 + r] = v.y;
            Ft[(3 + c4 + 2) * 128 + r] = v.z;
            Ft[(3 + c4 + 3) * 128 + r] = v.w;
        }
        if (t < 128) {
            const int n2 = s_idx[t];
            const int g = t >> 5;
            const float* xb = xyz + (size_t)b * 3 * NP;
            Ft[0 * 128 + t] = __fsub_rn(xb[n2],          s_q[g][0]);
            Ft[1 * 128 + t] = __fsub_rn(xb[NP + n2],     s_q[g][1]);
            Ft[2 * 128 + t] = __fsub_rn(xb[2 * NP + n2], s_q[g][2]);
        }
    }
    __syncthreads();
    const int rg = t >> 3;   // 0..31 -> rows rg*4..+3
    const int cg = t & 7;    // 0..7  -> cols cg*8..+7
    float4 ba = *(const float4*)(bias0 + cg * 8);
    float4 bb = *(const float4*)(bias0 + cg * 8 + 4);
    float acc[4][8];
#pragma unroll
    for (int j = 0; j < 4; ++j) {
        acc[j][0] = ba.x; acc[j][1] = ba.y; acc[j][2] = ba.z; acc[j][3] = ba.w;
        acc[j][4] = bb.x; acc[j][5] = bb.y; acc[j][6] = bb.z; acc[j][7] = bb.w;
    }
    for (int kk = 0; kk < 67; ++kk) {
        float4 f = *(const float4*)(Ft + kk * 128 + rg * 4);
        float4 wa = *(const float4*)(Ws + kk * 64 + cg * 8);
        float4 wb = *(const float4*)(Ws + kk * 64 + cg * 8 + 4);
        float fv[4] = {f.x, f.y, f.z, f.w};
        float wv[8] = {wa.x, wa.y, wa.z, wa.w, wb.x, wb.y, wb.z, wb.w};
#pragma unroll
        for (int j = 0; j < 4; ++j)
#pragma unroll
            for (int i = 0; i < 8; ++i) acc[j][i] = fmaf(fv[j], wv[i], acc[j][i]);
    }
    float ls[8] = {0,0,0,0,0,0,0,0}, lq[8] = {0,0,0,0,0,0,0,0};
#pragma unroll
    for (int j = 0; j < 4; ++j) {
        int m = m0 + rg * 4 + j;
        float4 oa = {acc[j][0], acc[j][1], acc[j][2], acc[j][3]};
        float4 ob = {acc[j][4], acc[j][5], acc[j][6], acc[j][7]};
        *(float4*)(h1 + (size_t)m * 64 + cg * 8) = oa;
        *(float4*)(h1 + (size_t)m * 64 + cg * 8 + 4) = ob;
#pragma unroll
        for (int i = 0; i < 8; ++i) { float v = acc[j][i]; ls[i] += v; lq[i] += v * v; }
    }
    __syncthreads();           // Ft reuse for stats partials
    float* part_s = Ft;        // [32][64]
    float* part_q = Ft + 2048; // [32][64]
#pragma unroll
    for (int i = 0; i < 8; ++i) { part_s[rg * 64 + cg * 8 + i] = ls[i]; part_q[rg * 64 + cg * 8 + i] = lq[i]; }
    __syncthreads();
    if (t < 64) {
        float s = 0.f, q = 0.f;
#pragma unroll
        for (int rgi = 0; rgi < 32; ++rgi) { s += part_s[rgi * 64 + t]; q += part_q[rgi * 64 + t]; }
        int cp = blockIdx.x & (NCOPY - 1);
        atomicAdd(&sum0[cp * 64 + t], s);
        atomicAdd(&ssq0[cp * 64 + t], q);
    }
}

// ---------------- layer2: BN1+ReLU on load + GEMM(64->64) + stats ----------------
__global__ __launch_bounds__(256) void k_layer2(const float* __restrict__ h1,
                                                const float* __restrict__ Wt1,
                                                const float* __restrict__ bias1,
                                                const float* __restrict__ ss1,
                                                float* __restrict__ h2,
                                                float* __restrict__ sum1,
                                                float* __restrict__ ssq1)
{
    __shared__ __align__(16) float Ft[64 * 128];
    __shared__ __align__(16) float Ws[64 * 64];
    __shared__ float s_sc[64], s_sh[64];
    const int t = threadIdx.x;
    const int m0 = blockIdx.x * 128;
    for (int i = t; i < 64 * 64; i += 256) Ws[i] = Wt1[i];
    if (t < 64) { s_sc[t] = ss1[t]; s_sh[t] = ss1[64 + t]; }
    __syncthreads();
    {
        const int tq = t >> 2, qq = t & 3;
#pragma unroll
        for (int rr = 0; rr < 2; ++rr) {
            const int r = rr * 64 + tq;
            const float* hrow = h1 + (size_t)(m0 + r) * 64;
#pragma unroll
            for (int rep = 0; rep < 4; ++rep) {
                const int c4 = qq * 4 + rep * 16;
                float4 v = *(const float4*)(hrow + c4);
                Ft[(c4 + 0) * 128 + r] = fmaxf(0.f, fmaf(v.x, s_sc[c4 + 0], s_sh[c4 + 0]));
                Ft[(c4 + 1) * 128 + r] = fmaxf(0.f, fmaf(v.y, s_sc[c4 + 1], s_sh[c4 + 1]));
                Ft[(c4 + 2) * 128 + r] = fmaxf(0.f, fmaf(v.z, s_sc[c4 + 2], s_sh[c4 + 2]));
                Ft[(c4 + 3) * 128 + r] = fmaxf(0.f, fmaf(v.w, s_sc[c4 + 3], s_sh[c4 + 3]));
            }
        }
    }
    __syncthreads();
    const int rg = t >> 3;
    const int cg = t & 7;
    float4 ba = *(const float4*)(bias1 + cg * 8);
    float4 bb = *(const float4*)(bias1 + cg * 8 + 4);
    float acc[4][8];
#pragma unroll
    for (int j = 0; j < 4; ++j) {
        acc[j][0] = ba.x; acc[j][1] = ba.y; acc[j][2] = ba.z; acc[j][3] = ba.w;
        acc[j][4] = bb.x; acc[j][5] = bb.y; acc[j][6] = bb.z; acc[j][7] = bb.w;
    }
    for (int kk = 0; kk < 64; ++kk) {
        float4 f = *(const float4*)(Ft + kk * 128 + rg * 4);
        float4 wa = *(const float4*)(Ws + kk * 64 + cg * 8);
        float4 wb = *(const float4*)(Ws + kk * 64 + cg * 8 + 4);
        float fv[4] = {f.x, f.y, f.z, f.w};
        float wv[8] = {wa.x, wa.y, wa.z, wa.w, wb.x, wb.y, wb.z, wb.w};
#pragma unroll
        for (int j = 0; j < 4; ++j)
#pragma unroll
            for (int i = 0; i < 8; ++i) acc[j][i] = fmaf(fv[j], wv[i], acc[j][i]);
    }
    float ls[8] = {0,0,0,0,0,0,0,0}, lq[8] = {0,0,0,0,0,0,0,0};
#pragma unroll
    for (int j = 0; j < 4; ++j) {
        int m = m0 + rg * 4 + j;
        float4 oa = {acc[j][0], acc[j][1], acc[j][2], acc[j][3]};
        float4 ob = {acc[j][4], acc[j][5], acc[j][6], acc[j][7]};
        *(float4*)(h2 + (size_t)m * 64 + cg * 8) = oa;
        *(float4*)(h2 + (size_t)m * 64 + cg * 8 + 4) = ob;
#pragma unroll
        for (int i = 0; i < 8; ++i) { float v = acc[j][i]; ls[i] += v; lq[i] += v * v; }
    }
    __syncthreads();
    float* part_s = Ft;
    float* part_q = Ft + 2048;
#pragma unroll
    for (int i = 0; i < 8; ++i) { part_s[rg * 64 + cg * 8 + i] = ls[i]; part_q[rg * 64 + cg * 8 + i] = lq[i]; }
    __syncthreads();
    if (t < 64) {
        float s = 0.f, q = 0.f;
#pragma unroll
        for (int rgi = 0; rgi < 32; ++rgi) { s += part_s[rgi * 64 + t]; q += part_q[rgi * 64 + t]; }
        int cp = blockIdx.x & (NCOPY - 1);
        atomicAdd(&sum1[cp * 64 + t], s);
        atomicAdd(&ssq1[cp * 64 + t], q);
    }
}

// ---------------- layer3: BN2+ReLU + GEMM(64->128) + stats + per-group max/min ----------------
// Pooling trick: max_k relu(a*h+b) == relu(a*max_k h + b) for a>=0 (min_k for a<0),
// exact in fp32 by monotonicity of fmaf/relu. So h3 is never materialized.
__global__ __launch_bounds__(256) void k_layer3(const float* __restrict__ h2,
                                                const float* __restrict__ Wt2,
                                                const float* __restrict__ bias2,
                                                const float* __restrict__ ss2,
                                                float* __restrict__ sum2,
                                                float* __restrict__ ssq2,
                                                float* __restrict__ gmax,
                                                float* __restrict__ gmin)
{
    __shared__ __align__(16) float Ft[64 * 128];
    __shared__ __align__(16) float Ws[64 * 128];
    __shared__ float s_sc[64], s_sh[64];
    const int t = threadIdx.x;
    const int m0 = blockIdx.x * 128;
    for (int i = t; i < 64 * 128; i += 256) Ws[i] = Wt2[i];
    if (t < 64) { s_sc[t] = ss2[t]; s_sh[t] = ss2[64 + t]; }
    __syncthreads();
    {
        const int tq = t >> 2, qq = t & 3;
#pragma unroll
        for (int rr = 0; rr < 2; ++rr) {
            const int r = rr * 64 + tq;
            const float* hrow = h2 + (size_t)(m0 + r) * 64;
#pragma unroll
            for (int rep = 0; rep < 4; ++rep) {
                const int c4 = qq * 4 + rep * 16;
                float4 v = *(const float4*)(hrow + c4);
                Ft[(c4 + 0) * 128 + r] = fmaxf(0.f, fmaf(v.x, s_sc[c4 + 0], s_sh[c4 + 0]));
                Ft[(c4 + 1) * 128 + r] = fmaxf(0.f, fmaf(v.y, s_sc[c4 + 1], s_sh[c4 + 1]));
                Ft[(c4 + 2) * 128 + r] = fmaxf(0.f, fmaf(v.z, s_sc[c4 + 2], s_sh[c4 + 2]));
                Ft[(c4 + 3) * 128 + r] = fmaxf(0.f, fmaf(v.w, s_sc[c4 + 3], s_sh[c4 + 3]));
            }
        }
    }
    __syncthreads();
    const int rg = t >> 4;  // 0..15 -> rows rg*8..+7  (all within group rg>>2)
    const int cg = t & 15;  // 0..15 -> cols cg*8..+7
    float4 ba = *(const float4*)(bias2 + cg * 8);
    float4 bb = *(const float4*)(bias2 + cg * 8 + 4);
    float acc[8][8];
#pragma unroll
    for (int j = 0; j < 8; ++j) {
        acc[j][0] = ba.x; acc[j][1] = ba.y; acc[j][2] = ba.z; acc[j][3] = ba.w;
        acc[j][4] = bb.x; acc[j][5] = bb.y; acc[j][6] = bb.z; acc[j][7] = bb.w;
    }
    for (int kk = 0; kk < 64; ++kk) {
        float4 fa = *(const float4*)(Ft + kk * 128 + rg * 8);
        float4 fb = *(const float4*)(Ft + kk * 128 + rg * 8 + 4);
        float4 wa = *(const float4*)(Ws + kk * 128 + cg * 8);
        float4 wb = *(const float4*)(Ws + kk * 128 + cg * 8 + 4);
        float fv[8] = {fa.x, fa.y, fa.z, fa.w, fb.x, fb.y, fb.z, fb.w};
        float wv[8] = {wa.x, wa.y, wa.z, wa.w, wb.x, wb.y, wb.z, wb.w};
#pragma unroll
        for (int j = 0; j < 8; ++j)
#pragma unroll
            for (int i = 0; i < 8; ++i) acc[j][i] = fmaf(fv[j], wv[i], acc[j][i]);
    }
    float ls[8] = {0,0,0,0,0,0,0,0}, lq[8] = {0,0,0,0,0,0,0,0};
    float pm[8], pn[8];
#pragma unroll
    for (int i = 0; i < 8; ++i) { pm[i] = acc[0][i]; pn[i] = acc[0][i]; }
#pragma unroll
    for (int j = 0; j < 8; ++j)
#pragma unroll
        for (int i = 0; i < 8; ++i) {
            float v = acc[j][i];
            ls[i] += v; lq[i] += v * v;
            pm[i] = fmaxf(pm[i], v); pn[i] = fminf(pn[i], v);
        }
    __syncthreads();
    float* part_s = Ft;        // [16][128]
    float* part_q = Ft + 2048; // [16][128]
    float* part_m = Ft + 4096; // [16][128]
    float* part_n = Ft + 6144; // [16][128]
#pragma unroll
    for (int i = 0; i < 8; ++i) {
        part_s[rg * 128 + cg * 8 + i] = ls[i];
        part_q[rg * 128 + cg * 8 + i] = lq[i];
        part_m[rg * 128 + cg * 8 + i] = pm[i];
        part_n[rg * 128 + cg * 8 + i] = pn[i];
    }
    __syncthreads();
    if (t < 128) {
        float s = 0.f, q = 0.f;
#pragma unroll
        for (int rgi = 0; rgi < 16; ++rgi) { s += part_s[rgi * 128 + t]; q += part_q[rgi * 128 + t]; }
        int cp = blockIdx.x & (NCOPY - 1);
        atomicAdd(&sum2[cp * 128 + t], s);
        atomicAdd(&ssq2[cp * 128 + t], q);
    }
    for (int e = t; e < 512; e += 256) {
        int g = e >> 7, c = e & 127;
        float M = part_m[(g * 4 + 0) * 128 + c];
        M = fmaxf(M, part_m[(g * 4 + 1) * 128 + c]);
        M = fmaxf(M, part_m[(g * 4 + 2) * 128 + c]);
        M = fmaxf(M, part_m[(g * 4 + 3) * 128 + c]);
        float N = part_n[(g * 4 + 0) * 128 + c];
        N = fminf(N, part_n[(g * 4 + 1) * 128 + c]);
        N = fminf(N, part_n[(g * 4 + 2) * 128 + c]);
        N = fminf(N, part_n[(g * 4 + 3) * 128 + c]);
        int grp = blockIdx.x * 4 + g;              // == b*1024 + s
        gmax[(size_t)grp * 128 + c] = M;
        gmin[(size_t)grp * 128 + c] = N;
    }
}

// ---------------- pool2: apply BN3+ReLU to pooled max/min, transposed store ----------------
__global__ __launch_bounds__(256) void k_pool2(const float* __restrict__ gmax,
                                               const float* __restrict__ gmin,
                                               const float* __restrict__ ss3,
                                               float* __restrict__ outp)
{
    int idx = blockIdx.x * 256 + threadIdx.x;      // 1,048,576 = 8*128*1024
    int b = idx >> 17;
    int c = (idx >> 10) & 127;
    int s = idx & 1023;
    int grp = (b << 10) + s;
    float a = ss3[c], sh = ss3[128 + c];
    float m = (a >= 0.f) ? gmax[(size_t)grp * 128 + c] : gmin[(size_t)grp * 128 + c];
    outp[idx] = fmaxf(0.f, fmaf(m, a, sh));
}

// ---------------- finalize BN stats -> scale/shift ----------------
__global__ void k_finalize(const float* __restrict__ sum, const float* __restrict__ ssq,
                           const float* __restrict__ g, const float* __restrict__ beta,
                           float* __restrict__ ss, int nc)
{
    int c = threadIdx.x;
    if (c >= nc) return;
    float s = 0.f, q = 0.f;
    for (int k = 0; k < NCOPY; ++k) { s += sum[k * nc + c]; q += ssq[k * nc + c]; }
    const float inv = 1.0f / 262144.0f;
    float mean = s * inv;
    float var = q * inv - mean * mean;
    float rstd = 1.0f / sqrtf(var + 1e-5f);
    float scale = g[c] * rstd;
    ss[c] = scale;
    ss[nc + c] = beta[c] - mean * scale;
}

extern "C" void kernel_launch(void* const* d_in, const int* in_sizes, int n_in,
                              void* d_out, int out_size, void* d_ws, size_t ws_size,
                              hipStream_t stream)
{
    const float* xyz    = (const float*)d_in[0];
    const float* points = (const float*)d_in[1];
    const float* w0 = (const float*)d_in[2];
    const float* b0 = (const float*)d_in[3];
    const float* gm0 = (const float*)d_in[4];
    const float* bt0 = (const float*)d_in[5];
    const float* w1 = (const float*)d_in[6];
    const float* b1 = (const float*)d_in[7];
    const float* gm1 = (const float*)d_in[8];
    const float* bt1 = (const float*)d_in[9];
    const float* w2 = (const float*)d_in[10];
    const float* b2 = (const float*)d_in[11];
    const float* gm2 = (const float*)d_in[12];
    const float* bt2 = (const float*)d_in[13];
    float* out = (float*)d_out;

    char* p = (char*)d_ws;
    auto alloc = [&](size_t nbytes) -> void* {
        void* r = (void*)p;
        p += (nbytes + 255) & ~(size_t)255;
        return r;
    };
    float* fps_pts = (float*)alloc((size_t)NB * SP * 3 * 4);
    int*   ball_idx = (int*)alloc((size_t)NB * SP * KS * 4);
    float* pts_t = (float*)alloc((size_t)NB * NP * CD * 4);
    float* h1 = (float*)alloc((size_t)MROWS * 64 * 4);
    float* h2 = (float*)alloc((size_t)MROWS * 64 * 4);
    float* gmax = (float*)alloc((size_t)NB * SP * 128 * 4);
    float* gmin = (float*)alloc((size_t)NB * SP * 128 * 4);
    float* Wt0 = (float*)alloc(67 * 64 * 4);
    float* Wt1 = (float*)alloc(64 * 64 * 4);
    float* Wt2 = (float*)alloc(64 * 128 * 4);
    float* stats = (float*)alloc(8192 * 4);
    float* ss1 = (float*)alloc(128 * 4);
    float* ss2 = (float*)alloc(128 * 4);
    float* ss3 = (float*)alloc(256 * 4);

    float* sum0 = stats;
    float* ssq0 = stats + 16 * 64;
    float* sum1 = stats + 2 * 16 * 64;
    float* ssq1 = stats + 3 * 16 * 64;
    float* sum2 = stats + 4 * 16 * 64;
    float* ssq2 = sum2 + 16 * 128;

    k_fps_pre<<<NB + NB * (NP / 64) + 1, 1024, 0, stream>>>(
        xyz, fps_pts, out, points, pts_t, w0, w1, w2, Wt0, Wt1, Wt2, stats);
    k_ballquery<<<(NB * SP) / 4, 256, 0, stream>>>(xyz, fps_pts, ball_idx);
    k_layer1<<<MROWS / 128, 256, 0, stream>>>(xyz, pts_t, fps_pts, ball_idx, Wt0, b0, h1, sum0, ssq0);
    k_finalize<<<1, 128, 0, stream>>>(sum0, ssq0, gm0, bt0, ss1, 64);
    k_layer2<<<MROWS / 128, 256, 0, stream>>>(h1, Wt1, b1, ss1, h2, sum1, ssq1);
    k_finalize<<<1, 128, 0, stream>>>(sum1, ssq1, gm1, bt1, ss2, 64);
    k_layer3<<<MROWS / 128, 256, 0, stream>>>(h2, Wt2, b2, ss2, sum2, ssq2, gmax, gmin);
    k_finalize<<<1, 128, 0, stream>>>(sum2, ssq2, gm2, bt2, ss3, 128);
    k_pool2<<<(NB * SP * 128) / 256, 256, 0, stream>>>(gmax, gmin, ss3, out + 24576);
}

// Round 11
// 1215.492 us; speedup vs baseline: 1.1959x; 1.1959x over previous
//
#include <hip/hip_runtime.h>

#define NB 8
#define NP 8192
#define SP 1024
#define KS 32
#define CD 64
#define MROWS (NB*SP*KS)
#define NCOPY 16

typedef float v2f __attribute__((ext_vector_type(2)));
typedef unsigned long long u64;

// one DPP max step on a u64 key: pure VALU, no LDS. ctrl is a template param because
// __builtin_amdgcn_update_dpp requires an immediate. old=src + bound_ctrl=false ->
// lanes with no valid source keep their own value (identity for max).
template <int CTRL>
__device__ __forceinline__ u64 dpp_max_step(u64 x) {
    int lo = (int)(unsigned)(x & 0xffffffffull);
    int hi = (int)(unsigned)(x >> 32);
    int slo = __builtin_amdgcn_update_dpp(lo, lo, CTRL, 0xf, 0xf, false);
    int shi = __builtin_amdgcn_update_dpp(hi, hi, CTRL, 0xf, 0xf, false);
    u64 y = ((u64)(unsigned)shi << 32) | (unsigned)slo;
    return x > y ? x : y;
}

// ---------------- fused FPS (blocks 0..7) + points-transpose (8..1031) + weight-prep (1032) ----------
// FPS: 512 thr (8 waves), 16 pts/thread, zero global mem in loop, ONE barrier/iter.
// key = (dist_bits<<32) | ~gid : u64 max == (max dist, tie -> min gid) for dist >= 0.
// Reduction: u64 DPP ladder (VALU-only) -> lane63 writes wave key (8 slots, parity dbuf)
//            -> barrier -> every wave DPP-reduces the 8 leader keys -> readlane -> b128 centroid.
// __launch_bounds__(512,1): cap 512 VGPR so the 64 data floats/thread stay in arch VGPRs
// (rounds 2-4 showed the default heuristic caps ~56 and spills).
__global__ __launch_bounds__(512, 1) void k_fps_pre(const float* __restrict__ xyz,
                                                    float* __restrict__ fps_pts,
                                                    float* __restrict__ out_nx,
                                                    const float* __restrict__ points,
                                                    float* __restrict__ pts_t,
                                                    const float* __restrict__ w0,
                                                    const float* __restrict__ w1,
                                                    const float* __restrict__ w2,
                                                    float* __restrict__ Wt0,
                                                    float* __restrict__ Wt1,
                                                    float* __restrict__ Wt2,
                                                    float* __restrict__ stats)
{
#pragma clang fp contract(off)
    __shared__ __align__(16) unsigned char smem[131072 + 256];
    const int blk = blockIdx.x;
    const int t = threadIdx.x;

    if (blk >= NB) {
        if (blk >= NB + NB * (NP / 64)) {
            // weight prep: zero stats, transpose weights to [kk][c]
            for (int i = t; i < 8192; i += 512) stats[i] = 0.f;
            for (int i = t; i < 64 * 67; i += 512) { int c = i / 67, kk = i % 67; Wt0[kk * 64 + c] = w0[i]; }
            for (int i = t; i < 64 * 64; i += 512) { int c = i >> 6, kk = i & 63; Wt1[kk * 64 + c] = w1[i]; }
            for (int i = t; i < 128 * 64; i += 512) { int c = i >> 6, kk = i & 63; Wt2[kk * 128 + c] = w2[i]; }
            return;
        }
        // points transpose (B,64,N) -> (B,N,64), 64x64 tile, 512 threads
        float (*tile)[65] = (float(*)[65])smem;
        const int tblk = blk - NB;
        const int b = tblk >> 7;
        const int n0 = (tblk & 127) << 6;
        const float* pb = points + (size_t)b * CD * NP;
        const int c = t & 63;
        const int dr = t >> 6;                 // 0..7
#pragma unroll
        for (int it = 0; it < 8; ++it) {
            int d = dr + it * 8;
            tile[d][c] = pb[(size_t)d * NP + n0 + c];
        }
        __syncthreads();
#pragma unroll
        for (int it = 0; it < 8; ++it) {
            int nn = dr + it * 8;
            pts_t[((size_t)b * NP + n0 + nn) * CD + c] = tile[c][nn];
        }
        return;
    }

    // ---- FPS path ----
    float4* s_p = (float4*)smem;               // 128 KB xyz mirror
    u64 (*s_wk)[8] = (u64(*)[8])(smem + 131072);
    const int b = blk;
    const int lane = t & 63, wid = t >> 6;     // 8 waves
    const float* xb = xyz + (size_t)b * 3 * NP;
    v2f px[8], py[8], pz[8], dv[8];
#pragma unroll
    for (int j = 0; j < 8; ++j) {
        const int n0 = t + (2 * j) * 512, n1 = n0 + 512;
        px[j] = (v2f){xb[n0], xb[n1]};
        py[j] = (v2f){xb[NP + n0], xb[NP + n1]};
        pz[j] = (v2f){xb[2 * NP + n0], xb[2 * NP + n1]};
        dv[j] = (v2f){1e10f, 1e10f};
        s_p[n0] = make_float4(px[j].x, py[j].x, pz[j].x, 0.f);
        s_p[n1] = make_float4(px[j].y, py[j].y, pz[j].y, 0.f);
    }
    float cx = xb[0], cy = xb[NP], cz = xb[2 * NP];
    float hx0 = 0.f, hy0 = 0.f, hz0 = 0.f;     // captured centroid of iteration i == t
    float hx1 = 0.f, hy1 = 0.f, hz1 = 0.f;     // captured centroid of iteration i == t + 512
    __syncthreads();
    for (int i = 0; i < SP; ++i) {
        if (i == t)       { hx0 = cx; hy0 = cy; hz0 = cz; }
        if (i == t + 512) { hx1 = cx; hy1 = cy; hz1 = cz; }
        // distance update + in-thread argmax (EXACT fp32: sub, mul, (x2+y2)+z2, min;
        // contract(off) forbids fma; ascending gid + strict > == first-index tie-break)
        float bv = -1.f; int bg = 0;
#pragma unroll
        for (int j = 0; j < 8; ++j) {
            v2f dx = px[j] - cx;
            v2f dy = py[j] - cy;
            v2f dz = pz[j] - cz;
            v2f d  = dx * dx + dy * dy;
            d = d + dz * dz;
            v2f dm = dv[j];
            dm.x = fminf(dm.x, d.x);
            dm.y = fminf(dm.y, d.y);
            dv[j] = dm;
            if (dm.x > bv) { bv = dm.x; bg = t + (2 * j) * 512; }
            if (dm.y > bv) { bv = dm.y; bg = t + (2 * j + 1) * 512; }
        }
        u64 bk = ((u64)__float_as_uint(bv) << 32) | (unsigned int)~bg;
        // per-wave DPP max ladder (VALU only); lane 63 ends with the wave max
        bk = dpp_max_step<0x111>(bk);          // row_shr:1
        bk = dpp_max_step<0x112>(bk);          // row_shr:2
        bk = dpp_max_step<0x114>(bk);          // row_shr:4
        bk = dpp_max_step<0x118>(bk);          // row_shr:8
        bk = dpp_max_step<0x142>(bk);          // row_bcast:15
        bk = dpp_max_step<0x143>(bk);          // row_bcast:31
        const int par = i & 1;
        if (lane == 63) s_wk[par][wid] = bk;   // plain overwrite, parity-dbuf'd
        __syncthreads();
        // every wave DPP-reduces the 8 leader keys (replicated twice per 16-lane row;
        // row ladder shr 1,2,4,8 -> lane 15 of each row = max over all 8 entries)
        u64 rk = s_wk[par][lane & 7];
        rk = dpp_max_step<0x111>(rk);
        rk = dpp_max_step<0x112>(rk);
        rk = dpp_max_step<0x114>(rk);
        rk = dpp_max_step<0x118>(rk);
        const int wg = ~__builtin_amdgcn_readlane((int)(unsigned)(rk & 0xffffffffull), 15);
        const float4 c = s_p[wg];              // uniform broadcast ds_read_b128
        cx = c.x; cy = c.y; cz = c.z;
        // safe without 2nd barrier: next write to s_wk[par] is 2 iters away, past the next barrier
    }
    // deferred outputs: thread t owns fps points t and t+512
    fps_pts[(b * SP + t) * 3 + 0] = hx0;
    fps_pts[(b * SP + t) * 3 + 1] = hy0;
    fps_pts[(b * SP + t) * 3 + 2] = hz0;
    fps_pts[(b * SP + t + 512) * 3 + 0] = hx1;
    fps_pts[(b * SP + t + 512) * 3 + 1] = hy1;
    fps_pts[(b * SP + t + 512) * 3 + 2] = hz1;
    out_nx[(size_t)b * 3 * SP + 0 * SP + t] = hx0;
    out_nx[(size_t)b * 3 * SP + 1 * SP + t] = hy0;
    out_nx[(size_t)b * 3 * SP + 2 * SP + t] = hz0;
    out_nx[(size_t)b * 3 * SP + 0 * SP + t + 512] = hx1;
    out_nx[(size_t)b * 3 * SP + 1 * SP + t + 512] = hy1;
    out_nx[(size_t)b * 3 * SP + 2 * SP + t + 512] = hz1;
}

// ---------------- ball query: one wave per query, ordered first-32 append ----------------
__global__ __launch_bounds__(256) void k_ballquery(const float* __restrict__ xyz,
                                                   const float* __restrict__ fps_pts,
                                                   int* __restrict__ ball_idx)
{
    const int wib = threadIdx.x >> 6;
    const int lane = threadIdx.x & 63;
    const int wid = blockIdx.x * 4 + wib;          // b*SP + s
    const int b = wid >> 10;
    const float* xb = xyz + (size_t)b * 3 * NP;
    const float qx = fps_pts[wid * 3 + 0];
    const float qy = fps_pts[wid * 3 + 1];
    const float qz = fps_pts[wid * 3 + 2];
    __shared__ int s_list[4][KS];
    int* list = s_list[wib];
    const float r2 = (float)(0.2 * 0.2);           // 0.039999999f — matches python double->f32
    int found = 0;
    for (int base = 0; base < NP && found < KS; base += 64) {
        int n = base + lane;
        float dx = __fsub_rn(qx, xb[n]);
        float dy = __fsub_rn(qy, xb[NP + n]);
        float dz = __fsub_rn(qz, xb[2 * NP + n]);
        float d = __fadd_rn(__fadd_rn(__fmul_rn(dx, dx), __fmul_rn(dy, dy)), __fmul_rn(dz, dz));
        bool in = !(d > r2);
        unsigned long long m = __ballot(in);
        int before = __popcll(m & ((1ull << lane) - 1ull));
        int pos = found + before;
        if (in && pos < KS) list[pos] = n;
        found += __popcll(m);
    }
    int first = list[0];
    if (lane < KS) {
        int v = (lane < found) ? list[lane] : first;
        ball_idx[wid * KS + lane] = v;
    }
}

// ---------------- layer1: gather(feat 67) + GEMM(67->64) + stats ----------------
__global__ __launch_bounds__(256) void k_layer1(const float* __restrict__ xyz,
                                                const float* __restrict__ pts_t,
                                                const float* __restrict__ fps_pts,
                                                const int* __restrict__ ball_idx,
                                                const float* __restrict__ Wt0,
                                                const float* __restrict__ bias0,
                                                float* __restrict__ h1,
                                                float* __restrict__ sum0,
                                                float* __restrict__ ssq0)
{
    __shared__ __align__(16) float Ft[67 * 128];
    __shared__ __align__(16) float Ws[67 * 64];
    __shared__ int   s_idx[128];
    __shared__ float s_q[4][3];
    const int t = threadIdx.x;
    const int m0 = blockIdx.x * 128;
    const int g0 = m0 >> 5;
    const int b = g0 >> 10;
    if (t < 128) s_idx[t] = ball_idx[g0 * KS + t];
    if (t < 12) ((float*)s_q)[t] = fps_pts[g0 * 3 + t];
    for (int i = t; i < 67 * 64; i += 256) Ws[i] = Wt0[i];
    __syncthreads();
    {
        const int r = t >> 1, half = t & 1;
        const int n = s_idx[r];
        const float* prow = pts_t + ((size_t)b * NP + n) * CD;
#pragma unroll
        for (int rep = 0; rep < 8; ++rep) {
            const int c4 = half * 4 + rep * 8;
            float4 v = *(const float4*)(prow + c4);
            Ft[(3 + c4 + 0) * 128 + r] = v.x;
            Ft[(3 + c4 + 1) * 128 + r] = v.y;
            Ft[(3 + c4 + 2) * 128 + r] = v.z;
            Ft[(3 + c4 + 3) * 128 + r] = v.w;
        }
        if (t < 128) {
            const int n2 = s_idx[t];
            const int g = t >> 5;
            const float* xb = xyz + (size_t)b * 3 * NP;
            Ft[0 * 128 + t] = __fsub_rn(xb[n2],          s_q[g][0]);
            Ft[1 * 128 + t] = __fsub_rn(xb[NP + n2],     s_q[g][1]);
            Ft[2 * 128 + t] = __fsub_rn(xb[2 * NP + n2], s_q[g][2]);
        }
    }
    __syncthreads();
    const int rg = t >> 3;   // 0..31 -> rows rg*4..+3
    const int cg = t & 7;    // 0..7  -> cols cg*8..+7
    float4 ba = *(const float4*)(bias0 + cg * 8);
    float4 bb = *(const float4*)(bias0 + cg * 8 + 4);
    float acc[4][8];
#pragma unroll
    for (int j = 0; j < 4; ++j) {
        acc[j][0] = ba.x; acc[j][1] = ba.y; acc[j][2] = ba.z; acc[j][3] = ba.w;
        acc[j][4] = bb.x; acc[j][5] = bb.y; acc[j][6] = bb.z; acc[j][7] = bb.w;
    }
    for (int kk = 0; kk < 67; ++kk) {
        float4 f = *(const float4*)(Ft + kk * 128 + rg * 4);
        float4 wa = *(const float4*)(Ws + kk * 64 + cg * 8);
        float4 wb = *(const float4*)(Ws + kk * 64 + cg * 8 + 4);
        float fv[4] = {f.x, f.y, f.z, f.w};
        float wv[8] = {wa.x, wa.y, wa.z, wa.w, wb.x, wb.y, wb.z, wb.w};
#pragma unroll
        for (int j = 0; j < 4; ++j)
#pragma unroll
            for (int i = 0; i < 8; ++i) acc[j][i] = fmaf(fv[j], wv[i], acc[j][i]);
    }
    float ls[8] = {0,0,0,0,0,0,0,0}, lq[8] = {0,0,0,0,0,0,0,0};
#pragma unroll
    for (int j = 0; j < 4; ++j) {
        int m = m0 + rg * 4 + j;
        float4 oa = {acc[j][0], acc[j][1], acc[j][2], acc[j][3]};
        float4 ob = {acc[j][4], acc[j][5], acc[j][6], acc[j][7]};
        *(float4*)(h1 + (size_t)m * 64 + cg * 8) = oa;
        *(float4*)(h1 + (size_t)m * 64 + cg * 8 + 4) = ob;
#pragma unroll
        for (int i = 0; i < 8; ++i) { float v = acc[j][i]; ls[i] += v; lq[i] += v * v; }
    }
    __syncthreads();           // Ft reuse for stats partials
    float* part_s = Ft;        // [32][64]
    float* part_q = Ft + 2048; // [32][64]
#pragma unroll
    for (int i = 0; i < 8; ++i) { part_s[rg * 64 + cg * 8 + i] = ls[i]; part_q[rg * 64 + cg * 8 + i] = lq[i]; }
    __syncthreads();
    if (t < 64) {
        float s = 0.f, q = 0.f;
#pragma unroll
        for (int rgi = 0; rgi < 32; ++rgi) { s += part_s[rgi * 64 + t]; q += part_q[rgi * 64 + t]; }
        int cp = blockIdx.x & (NCOPY - 1);
        atomicAdd(&sum0[cp * 64 + t], s);
        atomicAdd(&ssq0[cp * 64 + t], q);
    }
}

// ---------------- layer2: BN1+ReLU on load + GEMM(64->64) + stats ----------------
__global__ __launch_bounds__(256) void k_layer2(const float* __restrict__ h1,
                                                const float* __restrict__ Wt1,
                                                const float* __restrict__ bias1,
                                                const float* __restrict__ ss1,
                                                float* __restrict__ h2,
                                                float* __restrict__ sum1,
                                                float* __restrict__ ssq1)
{
    __shared__ __align__(16) float Ft[64 * 128];
    __shared__ __align__(16) float Ws[64 * 64];
    __shared__ float s_sc[64], s_sh[64];
    const int t = threadIdx.x;
    const int m0 = blockIdx.x * 128;
    for (int i = t; i < 64 * 64; i += 256) Ws[i] = Wt1[i];
    if (t < 64) { s_sc[t] = ss1[t]; s_sh[t] = ss1[64 + t]; }
    __syncthreads();
    {
        const int tq = t >> 2, qq = t & 3;
#pragma unroll
        for (int rr = 0; rr < 2; ++rr) {
            const int r = rr * 64 + tq;
            const float* hrow = h1 + (size_t)(m0 + r) * 64;
#pragma unroll
            for (int rep = 0; rep < 4; ++rep) {
                const int c4 = qq * 4 + rep * 16;
                float4 v = *(const float4*)(hrow + c4);
                Ft[(c4 + 0) * 128 + r] = fmaxf(0.f, fmaf(v.x, s_sc[c4 + 0], s_sh[c4 + 0]));
                Ft[(c4 + 1) * 128 + r] = fmaxf(0.f, fmaf(v.y, s_sc[c4 + 1], s_sh[c4 + 1]));
                Ft[(c4 + 2) * 128 + r] = fmaxf(0.f, fmaf(v.z, s_sc[c4 + 2], s_sh[c4 + 2]));
                Ft[(c4 + 3) * 128 + r] = fmaxf(0.f, fmaf(v.w, s_sc[c4 + 3], s_sh[c4 + 3]));
            }
        }
    }
    __syncthreads();
    const int rg = t >> 3;
    const int cg = t & 7;
    float4 ba = *(const float4*)(bias1 + cg * 8);
    float4 bb = *(const float4*)(bias1 + cg * 8 + 4);
    float acc[4][8];
#pragma unroll
    for (int j = 0; j < 4; ++j) {
        acc[j][0] = ba.x; acc[j][1] = ba.y; acc[j][2] = ba.z; acc[j][3] = ba.w;
        acc[j][4] = bb.x; acc[j][5] = bb.y; acc[j][6] = bb.z; acc[j][7] = bb.w;
    }
    for (int kk = 0; kk < 64; ++kk) {
        float4 f = *(const float4*)(Ft + kk * 128 + rg * 4);
        float4 wa = *(const float4*)(Ws + kk * 64 + cg * 8);
        float4 wb = *(const float4*)(Ws + kk * 64 + cg * 8 + 4);
        float fv[4] = {f.x, f.y, f.z, f.w};
        float wv[8] = {wa.x, wa.y, wa.z, wa.w, wb.x, wb.y, wb.z, wb.w};
#pragma unroll
        for (int j = 0; j < 4; ++j)
#pragma unroll
            for (int i = 0; i < 8; ++i) acc[j][i] = fmaf(fv[j], wv[i], acc[j][i]);
    }
    float ls[8] = {0,0,0,0,0,0,0,0}, lq[8] = {0,0,0,0,0,0,0,0};
#pragma unroll
    for (int j = 0; j < 4; ++j) {
        int m = m0 + rg * 4 + j;
        float4 oa = {acc[j][0], acc[j][1], acc[j][2], acc[j][3]};
        float4 ob = {acc[j][4], acc[j][5], acc[j][6], acc[j][7]};
        *(float4*)(h2 + (size_t)m * 64 + cg * 8) = oa;
        *(float4*)(h2 + (size_t)m * 64 + cg * 8 + 4) = ob;
#pragma unroll
        for (int i = 0; i < 8; ++i) { float v = acc[j][i]; ls[i] += v; lq[i] += v * v; }
    }
    __syncthreads();
    float* part_s = Ft;
    float* part_q = Ft + 2048;
#pragma unroll
    for (int i = 0; i < 8; ++i) { part_s[rg * 64 + cg * 8 + i] = ls[i]; part_q[rg * 64 + cg * 8 + i] = lq[i]; }
    __syncthreads();
    if (t < 64) {
        float s = 0.f, q = 0.f;
#pragma unroll
        for (int rgi = 0; rgi < 32; ++rgi) { s += part_s[rgi * 64 + t]; q += part_q[rgi * 64 + t]; }
        int cp = blockIdx.x & (NCOPY - 1);
        atomicAdd(&sum1[cp * 64 + t], s);
        atomicAdd(&ssq1[cp * 64 + t], q);
    }
}

// ---------------- layer3: BN2+ReLU + GEMM(64->128) + stats + per-group max/min ----------------
// Pooling trick: max_k relu(a*h+b) == relu(a*max_k h + b) for a>=0 (min_k for a<0),
// exact in fp32 by monotonicity of fmaf/relu. So h3 is never materialized.
__global__ __launch_bounds__(256) void k_layer3(const float* __restrict__ h2,
                                                const float* __restrict__ Wt2,
                                                const float* __restrict__ bias2,
                                                const float* __restrict__ ss2,
                                                float* __restrict__ sum2,
                                                float* __restrict__ ssq2,
                                                float* __restrict__ gmax,
                                                float* __restrict__ gmin)
{
    __shared__ __align__(16) float Ft[64 * 128];
    __shared__ __align__(16) float Ws[64 * 128];
    __shared__ float s_sc[64], s_sh[64];
    const int t = threadIdx.x;
    const int m0 = blockIdx.x * 128;
    for (int i = t; i < 64 * 128; i += 256) Ws[i] = Wt2[i];
    if (t < 64) { s_sc[t] = ss2[t]; s_sh[t] = ss2[64 + t]; }
    __syncthreads();
    {
        const int tq = t >> 2, qq = t & 3;
#pragma unroll
        for (int rr = 0; rr < 2; ++rr) {
            const int r = rr * 64 + tq;
            const float* hrow = h2 + (size_t)(m0 + r) * 64;
#pragma unroll
            for (int rep = 0; rep < 4; ++rep) {
                const int c4 = qq * 4 + rep * 16;
                float4 v = *(const float4*)(hrow + c4);
                Ft[(c4 + 0) * 128 + r] = fmaxf(0.f, fmaf(v.x, s_sc[c4 + 0], s_sh[c4 + 0]));
                Ft[(c4 + 1) * 128 + r] = fmaxf(0.f, fmaf(v.y, s_sc[c4 + 1], s_sh[c4 + 1]));
                Ft[(c4 + 2) * 128 + r] = fmaxf(0.f, fmaf(v.z, s_sc[c4 + 2], s_sh[c4 + 2]));
                Ft[(c4 + 3) * 128 + r] = fmaxf(0.f, fmaf(v.w, s_sc[c4 + 3], s_sh[c4 + 3]));
            }
        }
    }
    __syncthreads();
    const int rg = t >> 4;  // 0..15 -> rows rg*8..+7  (all within group rg>>2)
    const int cg = t & 15;  // 0..15 -> cols cg*8..+7
    float4 ba = *(const float4*)(bias2 + cg * 8);
    float4 bb = *(const float4*)(bias2 + cg * 8 + 4);
    float acc[8][8];
#pragma unroll
    for (int j = 0; j < 8; ++j) {
        acc[j][0] = ba.x; acc[j][1] = ba.y; acc[j][2] = ba.z; acc[j][3] = ba.w;
        acc[j][4] = bb.x; acc[j][5] = bb.y; acc[j][6] = bb.z; acc[j][7] = bb.w;
    }
    for (int kk = 0; kk < 64; ++kk) {
        float4 fa = *(const float4*)(Ft + kk * 128 + rg * 8);
        float4 fb = *(const float4*)(Ft + kk * 128 + rg * 8 + 4);
        float4 wa = *(const float4*)(Ws + kk * 128 + cg * 8);
        float4 wb = *(const float4*)(Ws + kk * 128 + cg * 8 + 4);
        float fv[8] = {fa.x, fa.y, fa.z, fa.w, fb.x, fb.y, fb.z, fb.w};
        float wv[8] = {wa.x, wa.y, wa.z, wa.w, wb.x, wb.y, wb.z, wb.w};
#pragma unroll
        for (int j = 0; j < 8; ++j)
#pragma unroll
            for (int i = 0; i < 8; ++i) acc[j][i] = fmaf(fv[j], wv[i], acc[j][i]);
    }
    float ls[8] = {0,0,0,0,0,0,0,0}, lq[8] = {0,0,0,0,0,0,0,0};
    float pm[8], pn[8];
#pragma unroll
    for (int i = 0; i < 8; ++i) { pm[i] = acc[0][i]; pn[i] = acc[0][i]; }
#pragma unroll
    for (int j = 0; j < 8; ++j)
#pragma unroll
        for (int i = 0; i < 8; ++i) {
            float v = acc[j][i];
            ls[i] += v; lq[i] += v * v;
            pm[i] = fmaxf(pm[i], v); pn[i] = fminf(pn[i], v);
        }
    __syncthreads();
    float* part_s = Ft;        // [16][128]
    float* part_q = Ft + 2048; // [16][128]
    float* part_m = Ft + 4096; // [16][128]
    float* part_n = Ft + 6144; // [16][128]
#pragma unroll
    for (int i = 0; i < 8; ++i) {
        part_s[rg * 128 + cg * 8 + i] = ls[i];
        part_q[rg * 128 + cg * 8 + i] = lq[i];
        part_m[rg * 128 + cg * 8 + i] = pm[i];
        part_n[rg * 128 + cg * 8 + i] = pn[i];
    }
    __syncthreads();
    if (t < 128) {
        float s = 0.f, q = 0.f;
#pragma unroll
        for (int rgi = 0; rgi < 16; ++rgi) { s += part_s[rgi * 128 + t]; q += part_q[rgi * 128 + t]; }
        int cp = blockIdx.x & (NCOPY - 1);
        atomicAdd(&sum2[cp * 128 + t], s);
        atomicAdd(&ssq2[cp * 128 + t], q);
    }
    for (int e = t; e < 512; e += 256) {
        int g = e >> 7, c = e & 127;
        float M = part_m[(g * 4 + 0) * 128 + c];
        M = fmaxf(M, part_m[(g * 4 + 1) * 128 + c]);
        M = fmaxf(M, part_m[(g * 4 + 2) * 128 + c]);
        M = fmaxf(M, part_m[(g * 4 + 3) * 128 + c]);
        float N = part_n[(g * 4 + 0) * 128 + c];
        N = fminf(N, part_n[(g * 4 + 1) * 128 + c]);
        N = fminf(N, part_n[(g * 4 + 2) * 128 + c]);
        N = fminf(N, part_n[(g * 4 + 3) * 128 + c]);
        int grp = blockIdx.x * 4 + g;              // == b*1024 + s
        gmax[(size_t)grp * 128 + c] = M;
        gmin[(size_t)grp * 128 + c] = N;
    }
}

// ---------------- pool2: apply BN3+ReLU to pooled max/min, transposed store ----------------
__global__ __launch_bounds__(256) void k_pool2(const float* __restrict__ gmax,
                                               const float* __restrict__ gmin,
                                               const float* __restrict__ ss3,
                                               float* __restrict__ outp)
{
    int idx = blockIdx.x * 256 + threadIdx.x;      // 1,048,576 = 8*128*1024
    int b = idx >> 17;
    int c = (idx >> 10) & 127;
    int s = idx & 1023;
    int grp = (b << 10) + s;
    float a = ss3[c], sh = ss3[128 + c];
    float m = (a >= 0.f) ? gmax[(size_t)grp * 128 + c] : gmin[(size_t)grp * 128 + c];
    outp[idx] = fmaxf(0.f, fmaf(m, a, sh));
}

// ---------------- finalize BN stats -> scale/shift ----------------
__global__ void k_finalize(const float* __restrict__ sum, const float* __restrict__ ssq,
                           const float* __restrict__ g, const float* __restrict__ beta,
                           float* __restrict__ ss, int nc)
{
    int c = threadIdx.x;
    if (c >= nc) return;
    float s = 0.f, q = 0.f;
    for (int k = 0; k < NCOPY; ++k) { s += sum[k * nc + c]; q += ssq[k * nc + c]; }
    const float inv = 1.0f / 262144.0f;
    float mean = s * inv;
    float var = q * inv - mean * mean;
    float rstd = 1.0f / sqrtf(var + 1e-5f);
    float scale = g[c] * rstd;
    ss[c] = scale;
    ss[nc + c] = beta[c] - mean * scale;
}

extern "C" void kernel_launch(void* const* d_in, const int* in_sizes, int n_in,
                              void* d_out, int out_size, void* d_ws, size_t ws_size,
                              hipStream_t stream)
{
    const float* xyz    = (const float*)d_in[0];
    const float* points = (const float*)d_in[1];
    const float* w0 = (const float*)d_in[2];
    const float* b0 = (const float*)d_in[3];
    const float* gm0 = (const float*)d_in[4];
    const float* bt0 = (const float*)d_in[5];
    const float* w1 = (const float*)d_in[6];
    const float* b1 = (const float*)d_in[7];
    const float* gm1 = (const float*)d_in[8];
    const float* bt1 = (const float*)d_in[9];
    const float* w2 = (const float*)d_in[10];
    const float* b2 = (const float*)d_in[11];
    const float* gm2 = (const float*)d_in[12];
    const float* bt2 = (const float*)d_in[13];
    float* out = (float*)d_out;

    char* p = (char*)d_ws;
    auto alloc = [&](size_t nbytes) -> void* {
        void* r = (void*)p;
        p += (nbytes + 255) & ~(size_t)255;
        return r;
    };
    float* fps_pts = (float*)alloc((size_t)NB * SP * 3 * 4);
    int*   ball_idx = (int*)alloc((size_t)NB * SP * KS * 4);
    float* pts_t = (float*)alloc((size_t)NB * NP * CD * 4);
    float* h1 = (float*)alloc((size_t)MROWS * 64 * 4);
    float* h2 = (float*)alloc((size_t)MROWS * 64 * 4);
    float* gmax = (float*)alloc((size_t)NB * SP * 128 * 4);
    float* gmin = (float*)alloc((size_t)NB * SP * 128 * 4);
    float* Wt0 = (float*)alloc(67 * 64 * 4);
    float* Wt1 = (float*)alloc(64 * 64 * 4);
    float* Wt2 = (float*)alloc(64 * 128 * 4);
    float* stats = (float*)alloc(8192 * 4);
    float* ss1 = (float*)alloc(128 * 4);
    float* ss2 = (float*)alloc(128 * 4);
    float* ss3 = (float*)alloc(256 * 4);

    float* sum0 = stats;
    float* ssq0 = stats + 16 * 64;
    float* sum1 = stats + 2 * 16 * 64;
    float* ssq1 = stats + 3 * 16 * 64;
    float* sum2 = stats + 4 * 16 * 64;
    float* ssq2 = sum2 + 16 * 128;

    k_fps_pre<<<NB + NB * (NP / 64) + 1, 512, 0, stream>>>(
        xyz, fps_pts, out, points, pts_t, w0, w1, w2, Wt0, Wt1, Wt2, stats);
    k_ballquery<<<(NB * SP) / 4, 256, 0, stream>>>(xyz, fps_pts, ball_idx);
    k_layer1<<<MROWS / 128, 256, 0, stream>>>(xyz, pts_t, fps_pts, ball_idx, Wt0, b0, h1, sum0, ssq0);
    k_finalize<<<1, 128, 0, stream>>>(sum0, ssq0, gm0, bt0, ss1, 64);
    k_layer2<<<MROWS / 128, 256, 0, stream>>>(h1, Wt1, b1, ss1, h2, sum1, ssq1);
    k_finalize<<<1, 128, 0, stream>>>(sum1, ssq1, gm1, bt1, ss2, 64);
    k_layer3<<<MROWS / 128, 256, 0, stream>>>(h2, Wt2, b2, ss2, sum2, ssq2, gmax, gmin);
    k_finalize<<<1, 128, 0, stream>>>(sum2, ssq2, gm2, bt2, ss3, 128);
    k_pool2<<<(NB * SP * 128) / 256, 256, 0, stream>>>(gmax, gmin, ss3, out + 24576);
}